// Round 4
// baseline (5284.569 us; speedup 1.0000x reference)
//
#include <hip/hip_runtime.h>
#include <hip/hip_bf16.h>

typedef __hip_bfloat16 bf16;

#define HWSZ 4096
#define CH 512
#define BATCH 4
#define NGROUPS 32
#define CPG 16

__device__ __forceinline__ float b2f(bf16 v) { return __bfloat162float(v); }
__device__ __forceinline__ bf16 f2b(float v) { return __float2bfloat16(v); }

// ---------------- GroupNorm stats: per-(b,c) scale/shift ----------------
// grid = B*32 blocks, 256 threads. sca[b,c] = rstd*gamma[c]; shf[b,c] = beta[c]-mu*rstd*gamma[c]
__global__ void gn_stats_kernel(const float* __restrict__ x, const float* __restrict__ gw,
                                const float* __restrict__ gb,
                                float* __restrict__ sca, float* __restrict__ shf) {
  int b = blockIdx.x >> 5, g = blockIdx.x & 31;
  size_t base = ((size_t)b * CH + (size_t)g * CPG) * HWSZ;
  const int N = CPG * HWSZ;  // 65536
  int tid = threadIdx.x;
  float s = 0.f, ss = 0.f;
  for (int i = tid; i < N; i += 256) {
    float v = x[base + i];
    s += v; ss += v * v;
  }
  __shared__ float rs[256], rss[256];
  rs[tid] = s; rss[tid] = ss;
  __syncthreads();
  for (int off = 128; off > 0; off >>= 1) {
    if (tid < off) { rs[tid] += rs[tid + off]; rss[tid] += rss[tid + off]; }
    __syncthreads();
  }
  if (tid < CPG) {
    float mu = rs[0] / (float)N;
    float var = rss[0] / (float)N - mu * mu;
    float inv = rsqrtf(var + 1e-6f);
    int c = g * CPG + tid;
    float a = inv * gw[c];
    sca[b * CH + c] = a;
    shf[b * CH + c] = gb[c] - mu * a;
  }
}

// ---------------- QKV conv1x1 with fused GN, ONE batch ----------------
// q/k/v are per-batch [CH][HWSZ] bf16. out[o,p] = sum_c W[o,c]*(a*x+b) + bias.
// grid (HW/64, C/64)
__global__ void qkv_kernel(const float* __restrict__ x,
                           const float* __restrict__ sca, const float* __restrict__ shf,
                           const float* __restrict__ qw, const float* __restrict__ qb,
                           const float* __restrict__ kw, const float* __restrict__ kb,
                           const float* __restrict__ vw, const float* __restrict__ vb,
                           bf16* __restrict__ q, bf16* __restrict__ k, bf16* __restrict__ v,
                           int b) {
  int p0 = blockIdx.x * 64;
  int o0 = blockIdx.y * 64;
  __shared__ float hs[16][64];
  __shared__ float wqs[16][64], wks[16][64], wvs[16][64];
  int tid = threadIdx.x;
  int tx = tid & 15, ty = tid >> 4;
  int l_k = tid >> 4;          // 0..15 channel-within-kstep
  int l_p = (tid & 15) * 4;    // 4 consecutive p
  int l_o = tid >> 2;          // 0..63 W row
  int l_kk = (tid & 3) * 4;    // 4 consecutive c
  float aq[4][4] = {}, ak[4][4] = {}, av[4][4] = {};
  for (int c0 = 0; c0 < CH; c0 += 16) {
    float ga = sca[b * CH + c0 + l_k];
    float gs = shf[b * CH + c0 + l_k];
    const float* xp = x + ((size_t)(b * CH + c0 + l_k)) * HWSZ + p0 + l_p;
    for (int t = 0; t < 4; ++t) hs[l_k][l_p + t] = ga * xp[t] + gs;
    const float* wqp = qw + (size_t)(o0 + l_o) * CH + c0 + l_kk;
    const float* wkp = kw + (size_t)(o0 + l_o) * CH + c0 + l_kk;
    const float* wvp = vw + (size_t)(o0 + l_o) * CH + c0 + l_kk;
    for (int t = 0; t < 4; ++t) {
      wqs[l_kk + t][l_o] = wqp[t];
      wks[l_kk + t][l_o] = wkp[t];
      wvs[l_kk + t][l_o] = wvp[t];
    }
    __syncthreads();
    for (int kk = 0; kk < 16; ++kk) {
      float bb[4], a1[4], a2[4], a3[4];
      for (int j = 0; j < 4; ++j) bb[j] = hs[kk][tx * 4 + j];
      for (int i = 0; i < 4; ++i) {
        a1[i] = wqs[kk][ty * 4 + i];
        a2[i] = wks[kk][ty * 4 + i];
        a3[i] = wvs[kk][ty * 4 + i];
      }
      for (int i = 0; i < 4; ++i)
        for (int j = 0; j < 4; ++j) {
          aq[i][j] += a1[i] * bb[j];
          ak[i][j] += a2[i] * bb[j];
          av[i][j] += a3[i] * bb[j];
        }
    }
    __syncthreads();
  }
  for (int i = 0; i < 4; ++i) {
    int o = o0 + ty * 4 + i;
    float bq = qb[o], bk = kb[o], bv = vb[o];
    size_t ob = (size_t)o * HWSZ + p0 + tx * 4;
    for (int j = 0; j < 4; ++j) {
      q[ob + j] = f2b(aq[i][j] + bq);
      k[ob + j] = f2b(ak[i][j] + bk);
      v[ob + j] = f2b(av[i][j] + bv);
    }
  }
}

// ---------------- S strip: attn[li, j] = scale * sum_c q[c, i0s+li] k[c, j] -------
// q/k per-batch [CH][HWSZ] bf16. grid (HW/64 j-tiles, rows/64 i-tiles)
__global__ void s_kernel(const bf16* __restrict__ q, const bf16* __restrict__ k,
                         bf16* __restrict__ attn, int i0s) {
  int j0 = blockIdx.x * 64;
  int il0 = blockIdx.y * 64;
  int i0 = i0s + il0;
  __shared__ float qs[16][64], ks[16][64];
  int tid = threadIdx.x;
  int tx = tid & 15, ty = tid >> 4;
  int l_k = tid >> 4;
  int l_p = (tid & 15) * 4;
  float acc[4][4] = {};
  for (int c0 = 0; c0 < CH; c0 += 16) {
    const bf16* qp = q + (size_t)(c0 + l_k) * HWSZ + i0 + l_p;
    const bf16* kp = k + (size_t)(c0 + l_k) * HWSZ + j0 + l_p;
    for (int t = 0; t < 4; ++t) {
      qs[l_k][l_p + t] = b2f(qp[t]);
      ks[l_k][l_p + t] = b2f(kp[t]);
    }
    __syncthreads();
    for (int kk = 0; kk < 16; ++kk) {
      float a[4], bb[4];
      for (int i = 0; i < 4; ++i) a[i] = qs[kk][ty * 4 + i];
      for (int j = 0; j < 4; ++j) bb[j] = ks[kk][tx * 4 + j];
      for (int i = 0; i < 4; ++i)
        for (int j = 0; j < 4; ++j) acc[i][j] += a[i] * bb[j];
    }
    __syncthreads();
  }
  const float scale = 0.044194173824159216f;  // 512^-0.5
  for (int i = 0; i < 4; ++i) {
    size_t ob = (size_t)(il0 + ty * 4 + i) * HWSZ + j0 + tx * 4;
    for (int j = 0; j < 4; ++j) attn[ob + j] = f2b(acc[i][j] * scale);
  }
}

// ---------------- row softmax in-place on attn strip (grid = rows blocks) --------
__global__ void softmax_kernel(bf16* __restrict__ attn) {
  int i = blockIdx.x;
  int tid = threadIdx.x;
  __shared__ float row[HWSZ];
  __shared__ float red[256];
  bf16* r = attn + (size_t)i * HWSZ;
  float m = -1e30f;
  for (int j = tid; j < HWSZ; j += 256) {
    float v = b2f(r[j]);
    row[j] = v;
    m = fmaxf(m, v);
  }
  red[tid] = m;
  __syncthreads();
  for (int off = 128; off > 0; off >>= 1) {
    if (tid < off) red[tid] = fmaxf(red[tid], red[tid + off]);
    __syncthreads();
  }
  m = red[0];
  __syncthreads();
  float s = 0.f;
  for (int j = tid; j < HWSZ; j += 256) {
    float e = __expf(row[j] - m);
    row[j] = e;
    s += e;
  }
  red[tid] = s;
  __syncthreads();
  for (int off = 128; off > 0; off >>= 1) {
    if (tid < off) red[tid] += red[tid + off];
    __syncthreads();
  }
  float inv = 1.0f / red[0];
  __syncthreads();
  for (int j = tid; j < HWSZ; j += 256) r[j] = f2b(row[j] * inv);
}

// ---------------- A strip: out[b,c,i0s+li] = x[b,c,i0s+li] + sum_j v[c,j] P[li,j] --
// v per-batch [CH][HWSZ] bf16. grid (rows/64 i-tiles, C/64 c-tiles)
__global__ void a_kernel(const bf16* __restrict__ v, const bf16* __restrict__ attn,
                         const float* __restrict__ x, float* __restrict__ out, int b, int i0s) {
  int il0 = blockIdx.x * 64;
  int c0 = blockIdx.y * 64;
  __shared__ float vt[16][64], pt[16][64];
  int tid = threadIdx.x;
  int tx = tid & 15, ty = tid >> 4;
  int l_r = tid >> 2;        // 0..63
  int l_j = (tid & 3) * 4;   // 4 consecutive j
  float acc[4][4] = {};
  for (int j0 = 0; j0 < HWSZ; j0 += 16) {
    const bf16* vp = v + (size_t)(c0 + l_r) * HWSZ + j0 + l_j;
    const bf16* pp = attn + (size_t)(il0 + l_r) * HWSZ + j0 + l_j;
    for (int t = 0; t < 4; ++t) {
      vt[l_j + t][l_r] = b2f(vp[t]);
      pt[l_j + t][l_r] = b2f(pp[t]);
    }
    __syncthreads();
    for (int jj = 0; jj < 16; ++jj) {
      float a[4], bb[4];
      for (int i = 0; i < 4; ++i) a[i] = vt[jj][ty * 4 + i];
      for (int j = 0; j < 4; ++j) bb[j] = pt[jj][tx * 4 + j];
      for (int i = 0; i < 4; ++i)
        for (int j = 0; j < 4; ++j) acc[i][j] += a[i] * bb[j];
    }
    __syncthreads();
  }
  for (int i = 0; i < 4; ++i) {
    size_t ob = ((size_t)(b * CH + c0 + ty * 4 + i)) * HWSZ + i0s + il0 + tx * 4;
    for (int j = 0; j < 4; ++j) out[ob + j] = x[ob + j] + acc[i][j];
  }
}

extern "C" void kernel_launch(void* const* d_in, const int* in_sizes, int n_in,
                              void* d_out, int out_size, void* d_ws, size_t ws_size,
                              hipStream_t stream) {
  const float* x   = (const float*)d_in[0];
  const float* gnw = (const float*)d_in[1];
  const float* gnb = (const float*)d_in[2];
  const float* qw  = (const float*)d_in[3];
  const float* qb  = (const float*)d_in[4];
  const float* kw  = (const float*)d_in[5];
  const float* kb  = (const float*)d_in[6];
  const float* vw  = (const float*)d_in[7];
  const float* vb  = (const float*)d_in[8];
  float* out = (float*)d_out;

  // ---- ws_size-adaptive layout (per-batch bf16 q/k/v; strip sized from what's left) ----
  // [ sca 8KB | shf 8KB | q 4MB | k 4MB | v 4MB | attn strip (rows x 4096 bf16) ]
  char* ws = (char*)d_ws;
  float* sca = (float*)ws;                       // BATCH*CH floats
  float* shf = sca + BATCH * CH;                 // BATCH*CH floats
  const size_t per = (size_t)CH * HWSZ;          // 2M elems = 4 MB bf16
  bf16* q = (bf16*)(ws + 16384);
  bf16* k = q + per;
  bf16* v = k + per;
  bf16* attn = v + per;
  size_t used = 16384 + 3 * per * sizeof(bf16);  // ~12.02 MB
  long rem = (long)ws_size - (long)used;
  long rows = rem / ((long)HWSZ * (long)sizeof(bf16));
  rows = (rows / 64) * 64;
  if (rows < 64) rows = 64;       // requires ws_size >= ~12.6 MB
  if (rows > 1024) rows = 1024;
  int strip = (int)rows;

  gn_stats_kernel<<<dim3(BATCH * NGROUPS), 256, 0, stream>>>(x, gnw, gnb, sca, shf);
  for (int b = 0; b < BATCH; ++b) {
    qkv_kernel<<<dim3(HWSZ / 64, CH / 64), 256, 0, stream>>>(x, sca, shf, qw, qb, kw, kb,
                                                             vw, vb, q, k, v, b);
    for (int i0s = 0; i0s < HWSZ; i0s += strip) {
      int rows_this = HWSZ - i0s < strip ? HWSZ - i0s : strip;
      s_kernel<<<dim3(HWSZ / 64, rows_this / 64), 256, 0, stream>>>(q, k, attn, i0s);
      softmax_kernel<<<dim3(rows_this), 256, 0, stream>>>(attn);
      a_kernel<<<dim3(rows_this / 64, CH / 64), 256, 0, stream>>>(v, attn, x, out, b, i0s);
    }
  }
}

// Round 5
// 1558.221 us; speedup vs baseline: 3.3914x; 3.3914x over previous
//
#include <hip/hip_runtime.h>
#include <hip/hip_bf16.h>

typedef __hip_bfloat16 bf16;
typedef __attribute__((ext_vector_type(8))) short short8;   // 8 bf16 MFMA frag
typedef __attribute__((ext_vector_type(4))) float f32x4;    // MFMA acc
typedef __attribute__((ext_vector_type(8))) unsigned short u16x8;

#define HWSZ 4096
#define CH 512
#define BATCH 4
#define NGROUPS 32
#define CPG 16
#define LDK 40      // padded LDS row stride (elements) for [m][32k] tiles; 80 B = 5*16 B
#define KSPLIT 8

__device__ __forceinline__ float b2f(bf16 v) { return __bfloat162float(v); }
__device__ __forceinline__ bf16 f2b(float v) { return __float2bfloat16(v); }

// ---------------- GroupNorm stats: per-(b,c) scale/shift ----------------
__global__ void gn_stats_kernel(const float* __restrict__ x, const float* __restrict__ gw,
                                const float* __restrict__ gb,
                                float* __restrict__ sca, float* __restrict__ shf) {
  int b = blockIdx.x >> 5, g = blockIdx.x & 31;
  size_t base = ((size_t)b * CH + (size_t)g * CPG) * HWSZ;
  const int N = CPG * HWSZ;
  int tid = threadIdx.x;
  float s = 0.f, ss = 0.f;
  for (int i = tid; i < N; i += 256) {
    float v = x[base + i];
    s += v; ss += v * v;
  }
  __shared__ float rs[256], rss[256];
  rs[tid] = s; rss[tid] = ss;
  __syncthreads();
  for (int off = 128; off > 0; off >>= 1) {
    if (tid < off) { rs[tid] += rs[tid + off]; rss[tid] += rss[tid + off]; }
    __syncthreads();
  }
  if (tid < CPG) {
    float mu = rs[0] / (float)N;
    float var = rss[0] / (float)N - mu * mu;
    float inv = rsqrtf(var + 1e-6f);
    int c = g * CPG + tid;
    float a = inv * gw[c];
    sca[b * CH + c] = a;
    shf[b * CH + c] = gb[c] - mu * a;
  }
}

// ---------------- QKV conv1x1 with fused GN, one batch (f32 VALU; known-correct) ----
__global__ void qkv_kernel(const float* __restrict__ x,
                           const float* __restrict__ sca, const float* __restrict__ shf,
                           const float* __restrict__ qw, const float* __restrict__ qb,
                           const float* __restrict__ kw, const float* __restrict__ kb,
                           const float* __restrict__ vw, const float* __restrict__ vb,
                           bf16* __restrict__ q, bf16* __restrict__ k, bf16* __restrict__ v,
                           int b) {
  int p0 = blockIdx.x * 64;
  int o0 = blockIdx.y * 64;
  __shared__ float hs[16][64];
  __shared__ float wqs[16][64], wks[16][64], wvs[16][64];
  int tid = threadIdx.x;
  int tx = tid & 15, ty = tid >> 4;
  int l_k = tid >> 4;
  int l_p = (tid & 15) * 4;
  int l_o = tid >> 2;
  int l_kk = (tid & 3) * 4;
  float aq[4][4] = {}, ak[4][4] = {}, av[4][4] = {};
  for (int c0 = 0; c0 < CH; c0 += 16) {
    float ga = sca[b * CH + c0 + l_k];
    float gs = shf[b * CH + c0 + l_k];
    const float* xp = x + ((size_t)(b * CH + c0 + l_k)) * HWSZ + p0 + l_p;
    for (int t = 0; t < 4; ++t) hs[l_k][l_p + t] = ga * xp[t] + gs;
    const float* wqp = qw + (size_t)(o0 + l_o) * CH + c0 + l_kk;
    const float* wkp = kw + (size_t)(o0 + l_o) * CH + c0 + l_kk;
    const float* wvp = vw + (size_t)(o0 + l_o) * CH + c0 + l_kk;
    for (int t = 0; t < 4; ++t) {
      wqs[l_kk + t][l_o] = wqp[t];
      wks[l_kk + t][l_o] = wkp[t];
      wvs[l_kk + t][l_o] = wvp[t];
    }
    __syncthreads();
    for (int kk = 0; kk < 16; ++kk) {
      float bb[4], a1[4], a2[4], a3[4];
      for (int j = 0; j < 4; ++j) bb[j] = hs[kk][tx * 4 + j];
      for (int i = 0; i < 4; ++i) {
        a1[i] = wqs[kk][ty * 4 + i];
        a2[i] = wks[kk][ty * 4 + i];
        a3[i] = wvs[kk][ty * 4 + i];
      }
      for (int i = 0; i < 4; ++i)
        for (int j = 0; j < 4; ++j) {
          aq[i][j] += a1[i] * bb[j];
          ak[i][j] += a2[i] * bb[j];
          av[i][j] += a3[i] * bb[j];
        }
    }
    __syncthreads();
  }
  for (int i = 0; i < 4; ++i) {
    int o = o0 + ty * 4 + i;
    float bq = qb[o], bk = kb[o], bv = vb[o];
    size_t ob = (size_t)o * HWSZ + p0 + tx * 4;
    for (int j = 0; j < 4; ++j) {
      q[ob + j] = f2b(aq[i][j] + bq);
      k[ob + j] = f2b(ak[i][j] + bk);
      v[ob + j] = f2b(av[i][j] + bv);
    }
  }
}

// ---------------- S strip via MFMA: attn[il][j] = scale * sum_c q[c][i]*k[c][j] ------
// 128x128 tile, BK=32. Operands are c-strided -> pack-transpose staging into [m][k] LDS.
__global__ __launch_bounds__(256) void s_mfma(const bf16* __restrict__ q,
                                              const bf16* __restrict__ k,
                                              bf16* __restrict__ attn, int i0s) {
  int j0 = blockIdx.x * 128;
  int il0 = blockIdx.y * 128;
  int i0 = i0s + il0;
  __shared__ __align__(16) bf16 lA[128 * LDK];
  __shared__ __align__(16) bf16 lB[128 * LDK];
  int tid = threadIdx.x;
  int l = tid & 63, w = tid >> 6;
  int quad = l >> 4, tm = l & 15;
  int wm = (w & 1) * 64, wn = (w >> 1) * 64;
  int kp = tid & 15;   // c-pair index (covers 32 c as 16 pairs)
  int mc = tid >> 4;   // m-chunk (8 rows each -> 128 rows)
  f32x4 acc[4][4] = {};
  for (int c0 = 0; c0 < CH; c0 += 32) {
    // pack-transpose staging: load 2 c-rows x 8 cols, pack (c,c+1) u16 pairs -> u32
    const bf16* g0 = q + (size_t)(c0 + 2 * kp) * HWSZ + i0 + mc * 8;
    u16x8 r0 = *(const u16x8*)g0;
    u16x8 r1 = *(const u16x8*)(g0 + HWSZ);
    const bf16* g2 = k + (size_t)(c0 + 2 * kp) * HWSZ + j0 + mc * 8;
    u16x8 s0 = *(const u16x8*)g2;
    u16x8 s1 = *(const u16x8*)(g2 + HWSZ);
    unsigned* uA = (unsigned*)lA;
    unsigned* uB = (unsigned*)lB;
#pragma unroll
    for (int t = 0; t < 8; ++t) {
      int m = mc * 8 + t;
      uA[m * (LDK / 2) + kp] = (unsigned)r0[t] | ((unsigned)r1[t] << 16);
      uB[m * (LDK / 2) + kp] = (unsigned)s0[t] | ((unsigned)s1[t] << 16);
    }
    __syncthreads();
    short8 aF[4], bF[4];
#pragma unroll
    for (int t = 0; t < 4; ++t) {
      aF[t] = *(const short8*)(lA + (wm + t * 16 + tm) * LDK + quad * 8);
      bF[t] = *(const short8*)(lB + (wn + t * 16 + tm) * LDK + quad * 8);
    }
#pragma unroll
    for (int mt = 0; mt < 4; ++mt)
#pragma unroll
      for (int nt = 0; nt < 4; ++nt)
        acc[mt][nt] = __builtin_amdgcn_mfma_f32_16x16x32_bf16(aF[mt], bF[nt], acc[mt][nt], 0, 0, 0);
    __syncthreads();
  }
  const float scale = 0.044194173824159216f;  // 512^-0.5
#pragma unroll
  for (int mt = 0; mt < 4; ++mt)
#pragma unroll
    for (int nt = 0; nt < 4; ++nt)
#pragma unroll
      for (int r = 0; r < 4; ++r) {
        int il = il0 + wm + mt * 16 + quad * 4 + r;  // C/D: row = quad*4+reg
        int j = j0 + wn + nt * 16 + tm;              //      col = lane&15
        attn[(size_t)il * HWSZ + j] = f2b(acc[mt][nt][r] * scale);
      }
}

// ---------------- row softmax in-place on attn strip ----------------
__global__ void softmax_kernel(bf16* __restrict__ attn) {
  int i = blockIdx.x;
  int tid = threadIdx.x;
  __shared__ float row[HWSZ];
  __shared__ float red[256];
  bf16* r = attn + (size_t)i * HWSZ;
  float m = -1e30f;
  for (int j = tid; j < HWSZ; j += 256) {
    float v = b2f(r[j]);
    row[j] = v;
    m = fmaxf(m, v);
  }
  red[tid] = m;
  __syncthreads();
  for (int off = 128; off > 0; off >>= 1) {
    if (tid < off) red[tid] = fmaxf(red[tid], red[tid + off]);
    __syncthreads();
  }
  m = red[0];
  __syncthreads();
  float s = 0.f;
  for (int j = tid; j < HWSZ; j += 256) {
    float e = __expf(row[j] - m);
    row[j] = e;
    s += e;
  }
  red[tid] = s;
  __syncthreads();
  for (int off = 128; off > 0; off >>= 1) {
    if (tid < off) red[tid] += red[tid + off];
    __syncthreads();
  }
  float inv = 1.0f / red[0];
  __syncthreads();
  for (int j = tid; j < HWSZ; j += 256) r[j] = f2b(row[j] * inv);
}

// ---------------- A strip via MFMA + split-K atomics ----------------
// acc_out[c][il] += sum_{j in chunk} v[c][j] * P[il][j].  Both operands j-contiguous.
__global__ __launch_bounds__(256) void a_mfma(const bf16* __restrict__ v,
                                              const bf16* __restrict__ attn,
                                              float* __restrict__ acc_out, int strip) {
  int il0 = blockIdx.x * 128;   // i tile (N dim)
  int c00 = blockIdx.y * 128;   // c tile (M dim)
  int kc = blockIdx.z;          // K chunk
  const int KC = HWSZ / KSPLIT; // 512
  int kbase = kc * KC;
  __shared__ __align__(16) bf16 lA[128 * LDK];
  __shared__ __align__(16) bf16 lB[128 * LDK];
  int tid = threadIdx.x;
  int l = tid & 63, w = tid >> 6;
  int quad = l >> 4, tm = l & 15;
  int wm = (w & 1) * 64, wn = (w >> 1) * 64;
  int sm = tid >> 1;            // staging row 0..127
  int sk = (tid & 1) * 16;      // staging col offset (elements)
  f32x4 acc[4][4] = {};
  for (int k0 = 0; k0 < KC; k0 += 32) {
    const bf16* ga = v + (size_t)(c00 + sm) * HWSZ + kbase + k0 + sk;
    const bf16* gb = attn + (size_t)(il0 + sm) * HWSZ + kbase + k0 + sk;
    *(u16x8*)(lA + sm * LDK + sk) = *(const u16x8*)ga;
    *(u16x8*)(lA + sm * LDK + sk + 8) = *(const u16x8*)(ga + 8);
    *(u16x8*)(lB + sm * LDK + sk) = *(const u16x8*)gb;
    *(u16x8*)(lB + sm * LDK + sk + 8) = *(const u16x8*)(gb + 8);
    __syncthreads();
    short8 aF[4], bF[4];
#pragma unroll
    for (int t = 0; t < 4; ++t) {
      aF[t] = *(const short8*)(lA + (wm + t * 16 + tm) * LDK + quad * 8);
      bF[t] = *(const short8*)(lB + (wn + t * 16 + tm) * LDK + quad * 8);
    }
#pragma unroll
    for (int mt = 0; mt < 4; ++mt)
#pragma unroll
      for (int nt = 0; nt < 4; ++nt)
        acc[mt][nt] = __builtin_amdgcn_mfma_f32_16x16x32_bf16(aF[mt], bF[nt], acc[mt][nt], 0, 0, 0);
    __syncthreads();
  }
#pragma unroll
  for (int mt = 0; mt < 4; ++mt)
#pragma unroll
    for (int nt = 0; nt < 4; ++nt)
#pragma unroll
      for (int r = 0; r < 4; ++r) {
        int c = c00 + wm + mt * 16 + quad * 4 + r;
        int il = il0 + wn + nt * 16 + tm;
        atomicAdd(&acc_out[(size_t)c * strip + il], acc[mt][nt][r]);
      }
}

// ---------------- out[b,c,i0s+il] = x + acc ----------------
__global__ void add_kernel(const float* __restrict__ x, const float* __restrict__ acc,
                           float* __restrict__ out, int b, int i0s, int strip, int rows) {
  int idx = blockIdx.x * 256 + threadIdx.x;  // one float4 per thread
  int per_row = rows >> 2;
  int c = idx / per_row;
  int r4 = (idx - c * per_row) * 4;
  size_t g = ((size_t)(b * CH + c)) * HWSZ + i0s + r4;
  const float4 xv = *(const float4*)(x + g);
  const float4 av = *(const float4*)(acc + (size_t)c * strip + r4);
  float4 o;
  o.x = xv.x + av.x; o.y = xv.y + av.y; o.z = xv.z + av.z; o.w = xv.w + av.w;
  *(float4*)(out + g) = o;
}

extern "C" void kernel_launch(void* const* d_in, const int* in_sizes, int n_in,
                              void* d_out, int out_size, void* d_ws, size_t ws_size,
                              hipStream_t stream) {
  const float* x   = (const float*)d_in[0];
  const float* gnw = (const float*)d_in[1];
  const float* gnb = (const float*)d_in[2];
  const float* qw  = (const float*)d_in[3];
  const float* qb  = (const float*)d_in[4];
  const float* kw  = (const float*)d_in[5];
  const float* kb  = (const float*)d_in[6];
  const float* vw  = (const float*)d_in[7];
  const float* vb  = (const float*)d_in[8];
  float* out = (float*)d_out;

  // ws: [ sca 8KB | shf 8KB | q 4MB | k 4MB | v 4MB | attn strip (bf16) | acc (f32) ]
  char* ws = (char*)d_ws;
  float* sca = (float*)ws;
  float* shf = sca + BATCH * CH;
  const size_t per = (size_t)CH * HWSZ;  // elems per batch tensor
  bf16* q = (bf16*)(ws + 16384);
  bf16* k = q + per;
  bf16* v = k + per;
  size_t used0 = 16384 + 3 * per * sizeof(bf16);  // ~12.02 MB
  // per strip-row: attn 4096*2 B + acc 512*4 B = 10240 B
  long rows = ((long)ws_size - (long)used0) / 10240;
  rows = (rows / 128) * 128;
  if (rows < 128) rows = 128;
  if (rows > 1024) rows = 1024;
  int strip = (int)rows;
  bf16* attn = v + per;
  float* acc = (float*)((char*)attn + (size_t)strip * HWSZ * sizeof(bf16));

  gn_stats_kernel<<<dim3(BATCH * NGROUPS), 256, 0, stream>>>(x, gnw, gnb, sca, shf);
  for (int b = 0; b < BATCH; ++b) {
    qkv_kernel<<<dim3(HWSZ / 64, CH / 64), 256, 0, stream>>>(x, sca, shf, qw, qb, kw, kb,
                                                             vw, vb, q, k, v, b);
    for (int i0s = 0; i0s < HWSZ; i0s += strip) {
      int rows_this = HWSZ - i0s < strip ? HWSZ - i0s : strip;
      s_mfma<<<dim3(HWSZ / 128, rows_this / 128), 256, 0, stream>>>(q, k, attn, i0s);
      softmax_kernel<<<dim3(rows_this), 256, 0, stream>>>(attn);
      hipMemsetAsync(acc, 0, (size_t)CH * strip * sizeof(float), stream);
      a_mfma<<<dim3(rows_this / 128, CH / 128, KSPLIT), 256, 0, stream>>>(v, attn, acc, strip);
      add_kernel<<<dim3((CH * rows_this) / 1024), 256, 0, stream>>>(x, acc, out, b, i0s,
                                                                    strip, rows_this);
    }
  }
}

// Round 7
// 1175.961 us; speedup vs baseline: 4.4938x; 1.3251x over previous
//
#include <hip/hip_runtime.h>
#include <hip/hip_bf16.h>

typedef __hip_bfloat16 bf16;
typedef __attribute__((ext_vector_type(8))) short short8;   // 8 bf16 MFMA frag
typedef __attribute__((ext_vector_type(4))) float f32x4;    // MFMA acc
typedef __attribute__((ext_vector_type(8))) unsigned short u16x8;
typedef __attribute__((ext_vector_type(4))) unsigned short u16x4;

#define HWSZ 4096
#define CH 512
#define BATCH 4
#define NGROUPS 32
#define CPG 16
#define LDK 40      // padded LDS row stride (elements); 80 B breaks pow2 bank strides
#define KSPLIT 8

__device__ __forceinline__ float b2f(bf16 v) { return __bfloat162float(v); }
__device__ __forceinline__ bf16 f2b(float v) { return __float2bfloat16(v); }

// ---------------- GroupNorm stats: per-(b,c) scale/shift ----------------
__global__ void gn_stats_kernel(const float* __restrict__ x, const float* __restrict__ gw,
                                const float* __restrict__ gb,
                                float* __restrict__ sca, float* __restrict__ shf) {
  int b = blockIdx.x >> 5, g = blockIdx.x & 31;
  size_t base = ((size_t)b * CH + (size_t)g * CPG) * HWSZ;
  const int N = CPG * HWSZ;
  int tid = threadIdx.x;
  float s = 0.f, ss = 0.f;
  for (int i = tid; i < N; i += 256) {
    float v = x[base + i];
    s += v; ss += v * v;
  }
  __shared__ float rs[256], rss[256];
  rs[tid] = s; rss[tid] = ss;
  __syncthreads();
  for (int off = 128; off > 0; off >>= 1) {
    if (tid < off) { rs[tid] += rs[tid + off]; rss[tid] += rss[tid + off]; }
    __syncthreads();
  }
  if (tid < CPG) {
    float mu = rs[0] / (float)N;
    float var = rss[0] / (float)N - mu * mu;
    float inv = rsqrtf(var + 1e-6f);
    int c = g * CPG + tid;
    float a = inv * gw[c];
    sca[b * CH + c] = a;
    shf[b * CH + c] = gb[c] - mu * a;
  }
}

// ---------------- weights f32 -> bf16 (once) ----------------
__global__ void wconv_kernel(const float* __restrict__ qw, const float* __restrict__ kw,
                             const float* __restrict__ vw,
                             bf16* __restrict__ wq, bf16* __restrict__ wk, bf16* __restrict__ wv) {
  int i = blockIdx.x * 256 + threadIdx.x;  // grid covers 512*512
  wq[i] = f2b(qw[i]);
  wk[i] = f2b(kw[i]);
  wv[i] = f2b(vw[i]);
}

// ---------------- h_apply: hT[p][c] = bf16(sca[c]*x[b,c,p]+shf[c]) (transpose) -------
// grid (HWSZ/64, CH/64), 256 threads, one batch
__global__ void h_apply_kernel(const float* __restrict__ x, const float* __restrict__ sca,
                               const float* __restrict__ shf, bf16* __restrict__ hT, int b) {
  int p0 = blockIdx.x * 64, c0 = blockIdx.y * 64;
  __shared__ bf16 lt[64][66];
  int t = threadIdx.x;
  int pp = (t & 15) * 4, ccb = t >> 4;
#pragma unroll
  for (int it = 0; it < 4; ++it) {
    int cc = ccb + it * 16;
    int c = c0 + cc;
    float a = sca[b * CH + c], s = shf[b * CH + c];
    const float4 xv = *(const float4*)(x + ((size_t)(b * CH + c)) * HWSZ + p0 + pp);
    lt[cc][pp] = f2b(a * xv.x + s);
    lt[cc][pp + 1] = f2b(a * xv.y + s);
    lt[cc][pp + 2] = f2b(a * xv.z + s);
    lt[cc][pp + 3] = f2b(a * xv.w + s);
  }
  __syncthreads();
  int cc = (t & 15) * 4;
#pragma unroll
  for (int it = 0; it < 4; ++it) {
    int pr = (t >> 4) + it * 16;
    u16x4 o;
#pragma unroll
    for (int j = 0; j < 4; ++j) o[j] = *(const unsigned short*)&lt[cc + j][pr];
    *(u16x4*)(hT + (size_t)(p0 + pr) * CH + c0 + cc) = o;
  }
}

// ---------------- QKV via MFMA (NT): T[p][o] = sum_c hT[p][c] W[o][c] + bias[o] ------
// z selects q/k/v. q,k stored transposed (qT[i][c]); v stored [c][j] via LDS transpose.
__global__ __launch_bounds__(256) void qkv_mfma(const bf16* __restrict__ hT,
                                                const bf16* __restrict__ wq,
                                                const bf16* __restrict__ wk,
                                                const bf16* __restrict__ wv,
                                                const float* __restrict__ qb,
                                                const float* __restrict__ kb,
                                                const float* __restrict__ vb,
                                                bf16* __restrict__ qT, bf16* __restrict__ kT,
                                                bf16* __restrict__ v) {
  int p0 = blockIdx.x * 128;
  int o0 = blockIdx.y * 128;
  int z = blockIdx.z;
  const bf16* W = z == 0 ? wq : (z == 1 ? wk : wv);
  const float* bias = z == 0 ? qb : (z == 1 ? kb : vb);
  __shared__ __align__(16) bf16 smem[2 * 128 * LDK];
  bf16* lA = smem;
  bf16* lB = smem + 128 * LDK;
  int tid = threadIdx.x;
  int l = tid & 63, w = tid >> 6;
  int quad = l >> 4, tm = l & 15;
  int wm = (w & 1) * 64, wn = (w >> 1) * 64;
  int sm = tid >> 1, sk = (tid & 1) * 16;
  f32x4 acc[4][4] = {};
  for (int c0 = 0; c0 < CH; c0 += 32) {
    const bf16* ga = hT + (size_t)(p0 + sm) * CH + c0 + sk;
    const bf16* gb = W + (size_t)(o0 + sm) * CH + c0 + sk;
    *(u16x8*)(lA + sm * LDK + sk) = *(const u16x8*)ga;
    *(u16x8*)(lA + sm * LDK + sk + 8) = *(const u16x8*)(ga + 8);
    *(u16x8*)(lB + sm * LDK + sk) = *(const u16x8*)gb;
    *(u16x8*)(lB + sm * LDK + sk + 8) = *(const u16x8*)(gb + 8);
    __syncthreads();
    short8 aF[4], bF[4];
#pragma unroll
    for (int t = 0; t < 4; ++t) {
      aF[t] = *(const short8*)(lA + (wm + t * 16 + tm) * LDK + quad * 8);
      bF[t] = *(const short8*)(lB + (wn + t * 16 + tm) * LDK + quad * 8);
    }
#pragma unroll
    for (int mt = 0; mt < 4; ++mt)
#pragma unroll
      for (int nt = 0; nt < 4; ++nt)
        acc[mt][nt] = __builtin_amdgcn_mfma_f32_16x16x32_bf16(aF[mt], bF[nt], acc[mt][nt], 0, 0, 0);
    __syncthreads();
  }
  if (z < 2) {
    bf16* outT = z == 0 ? qT : kT;
#pragma unroll
    for (int nt = 0; nt < 4; ++nt) {
      int o = o0 + wn + nt * 16 + tm;
      float bv = bias[o];
#pragma unroll
      for (int mt = 0; mt < 4; ++mt)
#pragma unroll
        for (int r = 0; r < 4; ++r) {
          int p = p0 + wm + mt * 16 + quad * 4 + r;
          outT[(size_t)p * CH + o] = f2b(acc[mt][nt][r] + bv);
        }
    }
  } else {
    // LDS transpose: v[o][p].  lt: 64 rows (o) x 136 cols (p), 16B-aligned rows
    bf16* lt = smem;  // 64*136 = 8704 elems <= 10240
    for (int chunk = 0; chunk < 2; ++chunk) {
      __syncthreads();
      if (wn == chunk * 64) {
#pragma unroll
        for (int nt = 0; nt < 4; ++nt) {
          int o = o0 + wn + nt * 16 + tm;
          float bv = bias[o];
#pragma unroll
          for (int mt = 0; mt < 4; ++mt)
#pragma unroll
            for (int r = 0; r < 4; ++r)
              lt[(nt * 16 + tm) * 136 + wm + mt * 16 + quad * 4 + r] = f2b(acc[mt][nt][r] + bv);
        }
      }
      __syncthreads();
      int oo = tid >> 2, ppb = (tid & 3) * 32;
      bf16* dst = v + (size_t)(o0 + chunk * 64 + oo) * HWSZ + p0 + ppb;
      const bf16* src = lt + oo * 136 + ppb;
#pragma unroll
      for (int q4 = 0; q4 < 4; ++q4)
        *(u16x8*)(dst + q4 * 8) = *(const u16x8*)(src + q4 * 8);
    }
  }
}

// ---------------- S strip via MFMA (NT): attn[il][j] = scale * sum_c qT[i][c] kT[j][c] --
__global__ __launch_bounds__(256) void s_mfma(const bf16* __restrict__ qT,
                                              const bf16* __restrict__ kT,
                                              bf16* __restrict__ attn, int i0s) {
  int j0 = blockIdx.x * 128;
  int il0 = blockIdx.y * 128;
  int i0 = i0s + il0;
  __shared__ __align__(16) bf16 lA[128 * LDK];
  __shared__ __align__(16) bf16 lB[128 * LDK];
  int tid = threadIdx.x;
  int l = tid & 63, w = tid >> 6;
  int quad = l >> 4, tm = l & 15;
  int wm = (w & 1) * 64, wn = (w >> 1) * 64;
  int sm = tid >> 1, sk = (tid & 1) * 16;
  f32x4 acc[4][4] = {};
  for (int c0 = 0; c0 < CH; c0 += 32) {
    const bf16* ga = qT + (size_t)(i0 + sm) * CH + c0 + sk;
    const bf16* gb = kT + (size_t)(j0 + sm) * CH + c0 + sk;
    *(u16x8*)(lA + sm * LDK + sk) = *(const u16x8*)ga;
    *(u16x8*)(lA + sm * LDK + sk + 8) = *(const u16x8*)(ga + 8);
    *(u16x8*)(lB + sm * LDK + sk) = *(const u16x8*)gb;
    *(u16x8*)(lB + sm * LDK + sk + 8) = *(const u16x8*)(gb + 8);
    __syncthreads();
    short8 aF[4], bF[4];
#pragma unroll
    for (int t = 0; t < 4; ++t) {
      aF[t] = *(const short8*)(lA + (wm + t * 16 + tm) * LDK + quad * 8);
      bF[t] = *(const short8*)(lB + (wn + t * 16 + tm) * LDK + quad * 8);
    }
#pragma unroll
    for (int mt = 0; mt < 4; ++mt)
#pragma unroll
      for (int nt = 0; nt < 4; ++nt)
        acc[mt][nt] = __builtin_amdgcn_mfma_f32_16x16x32_bf16(aF[mt], bF[nt], acc[mt][nt], 0, 0, 0);
    __syncthreads();
  }
  const float scale = 0.044194173824159216f;  // 512^-0.5
#pragma unroll
  for (int mt = 0; mt < 4; ++mt)
#pragma unroll
    for (int nt = 0; nt < 4; ++nt)
#pragma unroll
      for (int r = 0; r < 4; ++r) {
        int il = il0 + wm + mt * 16 + quad * 4 + r;
        int j = j0 + wn + nt * 16 + tm;
        attn[(size_t)il * HWSZ + j] = f2b(acc[mt][nt][r] * scale);
      }
}

// ---------------- row softmax in-place on attn strip ----------------
__global__ void softmax_kernel(bf16* __restrict__ attn) {
  int i = blockIdx.x;
  int tid = threadIdx.x;
  __shared__ float row[HWSZ];
  __shared__ float red[256];
  bf16* r = attn + (size_t)i * HWSZ;
  float m = -1e30f;
  for (int j = tid; j < HWSZ; j += 256) {
    float v = b2f(r[j]);
    row[j] = v;
    m = fmaxf(m, v);
  }
  red[tid] = m;
  __syncthreads();
  for (int off = 128; off > 0; off >>= 1) {
    if (tid < off) red[tid] = fmaxf(red[tid], red[tid + off]);
    __syncthreads();
  }
  m = red[0];
  __syncthreads();
  float s = 0.f;
  for (int j = tid; j < HWSZ; j += 256) {
    float e = __expf(row[j] - m);
    row[j] = e;
    s += e;
  }
  red[tid] = s;
  __syncthreads();
  for (int off = 128; off > 0; off >>= 1) {
    if (tid < off) red[tid] += red[tid + off];
    __syncthreads();
  }
  float inv = 1.0f / red[0];
  __syncthreads();
  for (int j = tid; j < HWSZ; j += 256) r[j] = f2b(row[j] * inv);
}

// ---------------- A strip via MFMA + split-K atomics ----------------
__global__ __launch_bounds__(256) void a_mfma(const bf16* __restrict__ v,
                                              const bf16* __restrict__ attn,
                                              float* __restrict__ acc_out, int strip) {
  int il0 = blockIdx.x * 128;
  int c00 = blockIdx.y * 128;
  int kc = blockIdx.z;
  const int KC = HWSZ / KSPLIT;
  int kbase = kc * KC;
  __shared__ __align__(16) bf16 lA[128 * LDK];
  __shared__ __align__(16) bf16 lB[128 * LDK];
  int tid = threadIdx.x;
  int l = tid & 63, w = tid >> 6;
  int quad = l >> 4, tm = l & 15;
  int wm = (w & 1) * 64, wn = (w >> 1) * 64;
  int sm = tid >> 1, sk = (tid & 1) * 16;
  f32x4 acc[4][4] = {};
  for (int k0 = 0; k0 < KC; k0 += 32) {
    const bf16* ga = v + (size_t)(c00 + sm) * HWSZ + kbase + k0 + sk;
    const bf16* gb = attn + (size_t)(il0 + sm) * HWSZ + kbase + k0 + sk;
    *(u16x8*)(lA + sm * LDK + sk) = *(const u16x8*)ga;
    *(u16x8*)(lA + sm * LDK + sk + 8) = *(const u16x8*)(ga + 8);
    *(u16x8*)(lB + sm * LDK + sk) = *(const u16x8*)gb;
    *(u16x8*)(lB + sm * LDK + sk + 8) = *(const u16x8*)(gb + 8);
    __syncthreads();
    short8 aF[4], bF[4];
#pragma unroll
    for (int t = 0; t < 4; ++t) {
      aF[t] = *(const short8*)(lA + (wm + t * 16 + tm) * LDK + quad * 8);
      bF[t] = *(const short8*)(lB + (wn + t * 16 + tm) * LDK + quad * 8);
    }
#pragma unroll
    for (int mt = 0; mt < 4; ++mt)
#pragma unroll
      for (int nt = 0; nt < 4; ++nt)
        acc[mt][nt] = __builtin_amdgcn_mfma_f32_16x16x32_bf16(aF[mt], bF[nt], acc[mt][nt], 0, 0, 0);
    __syncthreads();
  }
#pragma unroll
  for (int mt = 0; mt < 4; ++mt)
#pragma unroll
    for (int nt = 0; nt < 4; ++nt)
#pragma unroll
      for (int r = 0; r < 4; ++r) {
        int c = c00 + wm + mt * 16 + quad * 4 + r;
        int il = il0 + wn + nt * 16 + tm;
        atomicAdd(&acc_out[(size_t)c * strip + il], acc[mt][nt][r]);
      }
}

// ---------------- out[b,c,i0s+il] = x + acc ----------------
__global__ void add_kernel(const float* __restrict__ x, const float* __restrict__ acc,
                           float* __restrict__ out, int b, int i0s, int strip, int rows) {
  int idx = blockIdx.x * 256 + threadIdx.x;
  int per_row = rows >> 2;
  int c = idx / per_row;
  int r4 = (idx - c * per_row) * 4;
  size_t g = ((size_t)(b * CH + c)) * HWSZ + i0s + r4;
  const float4 xv = *(const float4*)(x + g);
  const float4 av = *(const float4*)(acc + (size_t)c * strip + r4);
  float4 o;
  o.x = xv.x + av.x; o.y = xv.y + av.y; o.z = xv.z + av.z; o.w = xv.w + av.w;
  *(float4*)(out + g) = o;
}

extern "C" void kernel_launch(void* const* d_in, const int* in_sizes, int n_in,
                              void* d_out, int out_size, void* d_ws, size_t ws_size,
                              hipStream_t stream) {
  const float* x   = (const float*)d_in[0];
  const float* gnw = (const float*)d_in[1];
  const float* gnb = (const float*)d_in[2];
  const float* qw  = (const float*)d_in[3];
  const float* qb  = (const float*)d_in[4];
  const float* kw  = (const float*)d_in[5];
  const float* kb  = (const float*)d_in[6];
  const float* vw  = (const float*)d_in[7];
  const float* vb  = (const float*)d_in[8];
  float* out = (float*)d_out;

  // ws: [sca|shf 16KB][wq|wk|wv bf16 1.5MB][hT 4MB][qT 4MB][kT 4MB][v 4MB][attn][acc]
  char* ws = (char*)d_ws;
  float* sca = (float*)ws;
  float* shf = sca + BATCH * CH;
  const size_t wsz = (size_t)CH * CH;          // 262144
  const size_t per = (size_t)CH * HWSZ;        // 2M elems
  bf16* wqb = (bf16*)(ws + 16384);
  bf16* wkb = wqb + wsz;
  bf16* wvb = wkb + wsz;
  bf16* hT = wvb + wsz;
  bf16* qT = hT + per;
  bf16* kT = qT + per;
  bf16* v  = kT + per;
  size_t used0 = 16384 + 3 * wsz * sizeof(bf16) + 4 * per * sizeof(bf16);  // ~17.5 MB
  long rows = ((long)ws_size - (long)used0) / 10240;  // attn 8KB + acc 2KB per row
  rows = (rows / 128) * 128;
  if (rows < 128) rows = 128;
  if (rows > 1024) rows = 1024;
  int strip = (int)rows;
  bf16* attn = v + per;
  float* acc = (float*)((char*)attn + (size_t)strip * HWSZ * sizeof(bf16));

  gn_stats_kernel<<<dim3(BATCH * NGROUPS), 256, 0, stream>>>(x, gnw, gnb, sca, shf);
  wconv_kernel<<<dim3(wsz / 256), 256, 0, stream>>>(qw, kw, vw, wqb, wkb, wvb);
  for (int b = 0; b < BATCH; ++b) {
    h_apply_kernel<<<dim3(HWSZ / 64, CH / 64), 256, 0, stream>>>(x, sca, shf, hT, b);
    qkv_mfma<<<dim3(HWSZ / 128, CH / 128, 3), 256, 0, stream>>>(hT, wqb, wkb, wvb, qb, kb, vb,
                                                                qT, kT, v);
    for (int i0s = 0; i0s < HWSZ; i0s += strip) {
      int rows_this = HWSZ - i0s < strip ? HWSZ - i0s : strip;
      s_mfma<<<dim3(HWSZ / 128, rows_this / 128), 256, 0, stream>>>(qT, kT, attn, i0s);
      softmax_kernel<<<dim3(rows_this), 256, 0, stream>>>(attn);
      hipMemsetAsync(acc, 0, (size_t)CH * strip * sizeof(float), stream);
      a_mfma<<<dim3(rows_this / 128, CH / 128, KSPLIT), 256, 0, stream>>>(v, attn, acc, strip);
      add_kernel<<<dim3((CH * rows_this) / 1024), 256, 0, stream>>>(x, acc, out, b, i0s,
                                                                    strip, rows_this);
    }
  }
}

// Round 8
// 652.686 us; speedup vs baseline: 8.0967x; 1.8017x over previous
//
#include <hip/hip_runtime.h>
#include <hip/hip_bf16.h>

typedef __hip_bfloat16 bf16;
typedef __attribute__((ext_vector_type(8))) short short8;   // 8 bf16 MFMA frag
typedef __attribute__((ext_vector_type(4))) float f32x4;    // MFMA acc
typedef __attribute__((ext_vector_type(8))) unsigned short u16x8;
typedef __attribute__((ext_vector_type(4))) unsigned short u16x4;

#define HWSZ 4096
#define CH 512
#define BATCH 4
#define NGROUPS 32
#define CPG 16
#define LDK 40      // padded LDS row stride (elements); 80 B breaks pow2 bank strides

__device__ __forceinline__ float b2f(bf16 v) { return __bfloat162float(v); }
__device__ __forceinline__ bf16 f2b(float v) { return __float2bfloat16(v); }
__device__ __forceinline__ float u2f(unsigned short u) {
  union { unsigned u; float f; } cv; cv.u = ((unsigned)u) << 16; return cv.f;
}

// ---------------- GN stage 1: partial sums, 8 chunks per (b,g) ----------------
// grid = B*32*8 blocks. gpart[bg*8+chunk] = {sum, sumsq} over 8192 elems.
__global__ void gn_part_kernel(const float* __restrict__ x, float2* __restrict__ gpart) {
  int bg = blockIdx.x >> 3, chunk = blockIdx.x & 7;
  size_t base = (size_t)bg * (CPG * HWSZ) + (size_t)chunk * 8192;
  int tid = threadIdx.x;
  float s = 0.f, ss = 0.f;
  const float4* xp = (const float4*)(x + base);
#pragma unroll
  for (int it = 0; it < 8; ++it) {
    float4 v = xp[tid + it * 256];
    s += v.x + v.y + v.z + v.w;
    ss += v.x * v.x + v.y * v.y + v.z * v.z + v.w * v.w;
  }
  __shared__ float rs[256], rss[256];
  rs[tid] = s; rss[tid] = ss;
  __syncthreads();
  for (int off = 128; off > 0; off >>= 1) {
    if (tid < off) { rs[tid] += rs[tid + off]; rss[tid] += rss[tid + off]; }
    __syncthreads();
  }
  if (tid == 0) gpart[blockIdx.x] = make_float2(rs[0], rss[0]);
}

// ---------------- GN stage 2: per-(b,c) scale/shift ----------------
// grid = 8 blocks x 256 threads -> 2048 (b,c) pairs
__global__ void gn_final_kernel(const float2* __restrict__ gpart,
                                const float* __restrict__ gw, const float* __restrict__ gb,
                                float* __restrict__ sca, float* __restrict__ shf) {
  int idx = blockIdx.x * 256 + threadIdx.x;  // b*CH + c
  int b = idx >> 9, c = idx & 511;
  int bg = b * NGROUPS + (c >> 4);
  float s = 0.f, ss = 0.f;
#pragma unroll
  for (int t = 0; t < 8; ++t) {
    float2 p = gpart[bg * 8 + t];
    s += p.x; ss += p.y;
  }
  const float N = (float)(CPG * HWSZ);
  float mu = s / N;
  float var = ss / N - mu * mu;
  float inv = rsqrtf(var + 1e-6f);
  float a = inv * gw[c];
  sca[idx] = a;
  shf[idx] = gb[c] - mu * a;
}

// ---------------- weights f32 -> bf16 (once) ----------------
__global__ void wconv_kernel(const float* __restrict__ qw, const float* __restrict__ kw,
                             const float* __restrict__ vw,
                             bf16* __restrict__ wq, bf16* __restrict__ wk, bf16* __restrict__ wv) {
  int i = blockIdx.x * 256 + threadIdx.x;
  wq[i] = f2b(qw[i]);
  wk[i] = f2b(kw[i]);
  wv[i] = f2b(vw[i]);
}

// ---------------- h_apply: hT[p][c] = bf16(sca[c]*x[b,c,p]+shf[c]) (transpose) -------
__global__ void h_apply_kernel(const float* __restrict__ x, const float* __restrict__ sca,
                               const float* __restrict__ shf, bf16* __restrict__ hT, int b) {
  int p0 = blockIdx.x * 64, c0 = blockIdx.y * 64;
  __shared__ bf16 lt[64][66];
  int t = threadIdx.x;
  int pp = (t & 15) * 4, ccb = t >> 4;
#pragma unroll
  for (int it = 0; it < 4; ++it) {
    int cc = ccb + it * 16;
    int c = c0 + cc;
    float a = sca[b * CH + c], s = shf[b * CH + c];
    const float4 xv = *(const float4*)(x + ((size_t)(b * CH + c)) * HWSZ + p0 + pp);
    lt[cc][pp] = f2b(a * xv.x + s);
    lt[cc][pp + 1] = f2b(a * xv.y + s);
    lt[cc][pp + 2] = f2b(a * xv.z + s);
    lt[cc][pp + 3] = f2b(a * xv.w + s);
  }
  __syncthreads();
  int cc = (t & 15) * 4;
#pragma unroll
  for (int it = 0; it < 4; ++it) {
    int pr = (t >> 4) + it * 16;
    u16x4 o;
#pragma unroll
    for (int j = 0; j < 4; ++j) o[j] = *(const unsigned short*)&lt[cc + j][pr];
    *(u16x4*)(hT + (size_t)(p0 + pr) * CH + c0 + cc) = o;
  }
}

// ---------------- QKV via MFMA (NT): T[p][o] = sum_c hT[p][c] W[o][c] + bias[o] ------
__global__ __launch_bounds__(256) void qkv_mfma(const bf16* __restrict__ hT,
                                                const bf16* __restrict__ wq,
                                                const bf16* __restrict__ wk,
                                                const bf16* __restrict__ wv,
                                                const float* __restrict__ qb,
                                                const float* __restrict__ kb,
                                                const float* __restrict__ vb,
                                                bf16* __restrict__ qT, bf16* __restrict__ kT,
                                                bf16* __restrict__ v) {
  int p0 = blockIdx.x * 128;
  int o0 = blockIdx.y * 128;
  int z = blockIdx.z;
  const bf16* W = z == 0 ? wq : (z == 1 ? wk : wv);
  const float* bias = z == 0 ? qb : (z == 1 ? kb : vb);
  __shared__ __align__(16) bf16 smem[2 * 128 * LDK];
  bf16* lA = smem;
  bf16* lB = smem + 128 * LDK;
  int tid = threadIdx.x;
  int l = tid & 63, w = tid >> 6;
  int quad = l >> 4, tm = l & 15;
  int wm = (w & 1) * 64, wn = (w >> 1) * 64;
  int sm = tid >> 1, sk = (tid & 1) * 16;
  f32x4 acc[4][4] = {};
  for (int c0 = 0; c0 < CH; c0 += 32) {
    const bf16* ga = hT + (size_t)(p0 + sm) * CH + c0 + sk;
    const bf16* gb = W + (size_t)(o0 + sm) * CH + c0 + sk;
    *(u16x8*)(lA + sm * LDK + sk) = *(const u16x8*)ga;
    *(u16x8*)(lA + sm * LDK + sk + 8) = *(const u16x8*)(ga + 8);
    *(u16x8*)(lB + sm * LDK + sk) = *(const u16x8*)gb;
    *(u16x8*)(lB + sm * LDK + sk + 8) = *(const u16x8*)(gb + 8);
    __syncthreads();
    short8 aF[4], bF[4];
#pragma unroll
    for (int t = 0; t < 4; ++t) {
      aF[t] = *(const short8*)(lA + (wm + t * 16 + tm) * LDK + quad * 8);
      bF[t] = *(const short8*)(lB + (wn + t * 16 + tm) * LDK + quad * 8);
    }
#pragma unroll
    for (int mt = 0; mt < 4; ++mt)
#pragma unroll
      for (int nt = 0; nt < 4; ++nt)
        acc[mt][nt] = __builtin_amdgcn_mfma_f32_16x16x32_bf16(aF[mt], bF[nt], acc[mt][nt], 0, 0, 0);
    __syncthreads();
  }
  if (z < 2) {
    bf16* outT = z == 0 ? qT : kT;
#pragma unroll
    for (int nt = 0; nt < 4; ++nt) {
      int o = o0 + wn + nt * 16 + tm;
      float bv = bias[o];
#pragma unroll
      for (int mt = 0; mt < 4; ++mt)
#pragma unroll
        for (int r = 0; r < 4; ++r) {
          int p = p0 + wm + mt * 16 + quad * 4 + r;
          outT[(size_t)p * CH + o] = f2b(acc[mt][nt][r] + bv);
        }
    }
  } else {
    // LDS transpose: v[o][p]
    bf16* lt = smem;
    for (int chunk = 0; chunk < 2; ++chunk) {
      __syncthreads();
      if (wn == chunk * 64) {
#pragma unroll
        for (int nt = 0; nt < 4; ++nt) {
          int o = o0 + wn + nt * 16 + tm;
          float bv = bias[o];
#pragma unroll
          for (int mt = 0; mt < 4; ++mt)
#pragma unroll
            for (int r = 0; r < 4; ++r)
              lt[(nt * 16 + tm) * 136 + wm + mt * 16 + quad * 4 + r] = f2b(acc[mt][nt][r] + bv);
        }
      }
      __syncthreads();
      int oo = tid >> 2, ppb = (tid & 3) * 32;
      bf16* dst = v + (size_t)(o0 + chunk * 64 + oo) * HWSZ + p0 + ppb;
      const bf16* src = lt + oo * 136 + ppb;
#pragma unroll
      for (int q4 = 0; q4 < 4; ++q4)
        *(u16x8*)(dst + q4 * 8) = *(const u16x8*)(src + q4 * 8);
    }
  }
}

// ---------------- S strip via MFMA (NT) ----------------
__global__ __launch_bounds__(256) void s_mfma(const bf16* __restrict__ qT,
                                              const bf16* __restrict__ kT,
                                              bf16* __restrict__ attn, int i0s) {
  int j0 = blockIdx.x * 128;
  int il0 = blockIdx.y * 128;
  int i0 = i0s + il0;
  __shared__ __align__(16) bf16 lA[128 * LDK];
  __shared__ __align__(16) bf16 lB[128 * LDK];
  int tid = threadIdx.x;
  int l = tid & 63, w = tid >> 6;
  int quad = l >> 4, tm = l & 15;
  int wm = (w & 1) * 64, wn = (w >> 1) * 64;
  int sm = tid >> 1, sk = (tid & 1) * 16;
  f32x4 acc[4][4] = {};
  for (int c0 = 0; c0 < CH; c0 += 32) {
    const bf16* ga = qT + (size_t)(i0 + sm) * CH + c0 + sk;
    const bf16* gb = kT + (size_t)(j0 + sm) * CH + c0 + sk;
    *(u16x8*)(lA + sm * LDK + sk) = *(const u16x8*)ga;
    *(u16x8*)(lA + sm * LDK + sk + 8) = *(const u16x8*)(ga + 8);
    *(u16x8*)(lB + sm * LDK + sk) = *(const u16x8*)gb;
    *(u16x8*)(lB + sm * LDK + sk + 8) = *(const u16x8*)(gb + 8);
    __syncthreads();
    short8 aF[4], bF[4];
#pragma unroll
    for (int t = 0; t < 4; ++t) {
      aF[t] = *(const short8*)(lA + (wm + t * 16 + tm) * LDK + quad * 8);
      bF[t] = *(const short8*)(lB + (wn + t * 16 + tm) * LDK + quad * 8);
    }
#pragma unroll
    for (int mt = 0; mt < 4; ++mt)
#pragma unroll
      for (int nt = 0; nt < 4; ++nt)
        acc[mt][nt] = __builtin_amdgcn_mfma_f32_16x16x32_bf16(aF[mt], bF[nt], acc[mt][nt], 0, 0, 0);
    __syncthreads();
  }
  const float scale = 0.044194173824159216f;  // 512^-0.5
#pragma unroll
  for (int mt = 0; mt < 4; ++mt)
#pragma unroll
    for (int nt = 0; nt < 4; ++nt)
#pragma unroll
      for (int r = 0; r < 4; ++r) {
        int il = il0 + wm + mt * 16 + quad * 4 + r;
        int j = j0 + wn + nt * 16 + tm;
        attn[(size_t)il * HWSZ + j] = f2b(acc[mt][nt][r] * scale);
      }
}

// ---------------- row softmax, vectorized u16x8 ----------------
__global__ void softmax_kernel(bf16* __restrict__ attn) {
  int i = blockIdx.x;
  int tid = threadIdx.x;
  __shared__ float row[HWSZ];
  __shared__ float red[256];
  u16x8* r = (u16x8*)(attn + (size_t)i * HWSZ);
  float m = -1e30f;
#pragma unroll
  for (int it = 0; it < 2; ++it) {
    int j8 = tid + it * 256;
    u16x8 rv = r[j8];
#pragma unroll
    for (int t = 0; t < 8; ++t) {
      float v = u2f(rv[t]);
      row[j8 * 8 + t] = v;
      m = fmaxf(m, v);
    }
  }
  red[tid] = m;
  __syncthreads();
  for (int off = 128; off > 0; off >>= 1) {
    if (tid < off) red[tid] = fmaxf(red[tid], red[tid + off]);
    __syncthreads();
  }
  m = red[0];
  __syncthreads();
  float s = 0.f;
  for (int j = tid; j < HWSZ; j += 256) {
    float e = __expf(row[j] - m);
    row[j] = e;
    s += e;
  }
  red[tid] = s;
  __syncthreads();
  for (int off = 128; off > 0; off >>= 1) {
    if (tid < off) red[tid] += red[tid + off];
    __syncthreads();
  }
  float inv = 1.0f / red[0];
  __syncthreads();
#pragma unroll
  for (int it = 0; it < 2; ++it) {
    int j8 = tid + it * 256;
    u16x8 ov;
#pragma unroll
    for (int t = 0; t < 8; ++t) ov[t] = *(unsigned short*)&(*(bf16*)&(bf16&)(((bf16*)nullptr)[0]));  // placeholder
    // real pack below
    (void)ov;
    u16x8 o;
#pragma unroll
    for (int t = 0; t < 8; ++t) {
      bf16 bv = f2b(row[j8 * 8 + t] * inv);
      o[t] = *(unsigned short*)&bv;
    }
    r[j8] = o;
  }
}

// ---------------- A strip via MFMA + split-K atomics ----------------
__global__ __launch_bounds__(256) void a_mfma(const bf16* __restrict__ v,
                                              const bf16* __restrict__ attn,
                                              float* __restrict__ acc_out, int strip, int KC) {
  int il0 = blockIdx.x * 128;
  int c00 = blockIdx.y * 128;
  int kbase = blockIdx.z * KC;
  __shared__ __align__(16) bf16 lA[128 * LDK];
  __shared__ __align__(16) bf16 lB[128 * LDK];
  int tid = threadIdx.x;
  int l = tid & 63, w = tid >> 6;
  int quad = l >> 4, tm = l & 15;
  int wm = (w & 1) * 64, wn = (w >> 1) * 64;
  int sm = tid >> 1, sk = (tid & 1) * 16;
  f32x4 acc[4][4] = {};
  for (int k0 = 0; k0 < KC; k0 += 32) {
    const bf16* ga = v + (size_t)(c00 + sm) * HWSZ + kbase + k0 + sk;
    const bf16* gb = attn + (size_t)(il0 + sm) * HWSZ + kbase + k0 + sk;
    *(u16x8*)(lA + sm * LDK + sk) = *(const u16x8*)ga;
    *(u16x8*)(lA + sm * LDK + sk + 8) = *(const u16x8*)(ga + 8);
    *(u16x8*)(lB + sm * LDK + sk) = *(const u16x8*)gb;
    *(u16x8*)(lB + sm * LDK + sk + 8) = *(const u16x8*)(gb + 8);
    __syncthreads();
    short8 aF[4], bF[4];
#pragma unroll
    for (int t = 0; t < 4; ++t) {
      aF[t] = *(const short8*)(lA + (wm + t * 16 + tm) * LDK + quad * 8);
      bF[t] = *(const short8*)(lB + (wn + t * 16 + tm) * LDK + quad * 8);
    }
#pragma unroll
    for (int mt = 0; mt < 4; ++mt)
#pragma unroll
      for (int nt = 0; nt < 4; ++nt)
        acc[mt][nt] = __builtin_amdgcn_mfma_f32_16x16x32_bf16(aF[mt], bF[nt], acc[mt][nt], 0, 0, 0);
    __syncthreads();
  }
#pragma unroll
  for (int mt = 0; mt < 4; ++mt)
#pragma unroll
    for (int nt = 0; nt < 4; ++nt)
#pragma unroll
      for (int r = 0; r < 4; ++r) {
        int c = c00 + wm + mt * 16 + quad * 4 + r;
        int il = il0 + wn + nt * 16 + tm;
        atomicAdd(&acc_out[(size_t)c * strip + il], acc[mt][nt][r]);
      }
}

// ---------------- out[b,c,i0s+il] = x + acc ----------------
__global__ void add_kernel(const float* __restrict__ x, const float* __restrict__ acc,
                           float* __restrict__ out, int b, int i0s, int strip, int rows) {
  int idx = blockIdx.x * 256 + threadIdx.x;
  int per_row = rows >> 2;
  int c = idx / per_row;
  int r4 = (idx - c * per_row) * 4;
  size_t g = ((size_t)(b * CH + c)) * HWSZ + i0s + r4;
  const float4 xv = *(const float4*)(x + g);
  const float4 av = *(const float4*)(acc + (size_t)c * strip + r4);
  float4 o;
  o.x = xv.x + av.x; o.y = xv.y + av.y; o.z = xv.z + av.z; o.w = xv.w + av.w;
  *(float4*)(out + g) = o;
}

extern "C" void kernel_launch(void* const* d_in, const int* in_sizes, int n_in,
                              void* d_out, int out_size, void* d_ws, size_t ws_size,
                              hipStream_t stream) {
  const float* x   = (const float*)d_in[0];
  const float* gnw = (const float*)d_in[1];
  const float* gnb = (const float*)d_in[2];
  const float* qw  = (const float*)d_in[3];
  const float* qb  = (const float*)d_in[4];
  const float* kw  = (const float*)d_in[5];
  const float* kb  = (const float*)d_in[6];
  const float* vw  = (const float*)d_in[7];
  const float* vb  = (const float*)d_in[8];
  float* out = (float*)d_out;

  // ws: [sca 8K|shf 8K|gpart 8K|pad -> 32K][wq|wk|wv 1.5MB][hT 4MB][qT 4MB][kT 4MB][v 4MB][attn][acc]
  char* ws = (char*)d_ws;
  float* sca = (float*)ws;
  float* shf = sca + BATCH * CH;
  float2* gpart = (float2*)(ws + 16384);       // 1024 float2 = 8 KB
  const size_t wsz = (size_t)CH * CH;
  const size_t per = (size_t)CH * HWSZ;
  bf16* wqb = (bf16*)(ws + 32768);
  bf16* wkb = wqb + wsz;
  bf16* wvb = wkb + wsz;
  bf16* hT = wvb + wsz;
  bf16* qT = hT + per;
  bf16* kT = qT + per;
  bf16* v  = kT + per;
  size_t used0 = 32768 + 3 * wsz * sizeof(bf16) + 4 * per * sizeof(bf16);  // ~17.5 MB
  long rows = ((long)ws_size - (long)used0) / 10240;  // attn 8KB + acc 2KB per row
  rows = (rows / 128) * 128;
  if (rows < 128) rows = 128;
  if (rows > 4096) rows = 4096;
  int strip = (int)rows;
  bf16* attn = v + per;
  float* acc = (float*)((char*)attn + (size_t)strip * HWSZ * sizeof(bf16));

  gn_part_kernel<<<dim3(BATCH * NGROUPS * 8), 256, 0, stream>>>(x, gpart);
  gn_final_kernel<<<dim3(8), 256, 0, stream>>>(gpart, gnw, gnb, sca, shf);
  wconv_kernel<<<dim3(wsz / 256), 256, 0, stream>>>(qw, kw, vw, wqb, wkb, wvb);
  for (int b = 0; b < BATCH; ++b) {
    h_apply_kernel<<<dim3(HWSZ / 64, CH / 64), 256, 0, stream>>>(x, sca, shf, hT, b);
    qkv_mfma<<<dim3(HWSZ / 128, CH / 128, 3), 256, 0, stream>>>(hT, wqb, wkb, wvb, qb, kb, vb,
                                                                qT, kT, v);
    for (int i0s = 0; i0s < HWSZ; i0s += strip) {
      int rows_this = HWSZ - i0s < strip ? HWSZ - i0s : strip;
      int itiles = rows_this / 128;
      int ksplit = 256 / (itiles * (CH / 128));
      if (ksplit < 1) ksplit = 1;
      if (ksplit > 8) ksplit = 8;
      // round down to power of two dividing HWSZ into 32-multiples (1,2,4,8 all ok)
      while (ksplit & (ksplit - 1)) --ksplit;
      int KC = HWSZ / ksplit;
      s_mfma<<<dim3(HWSZ / 128, itiles), 256, 0, stream>>>(qT, kT, attn, i0s);
      softmax_kernel<<<dim3(rows_this), 256, 0, stream>>>(attn);
      hipMemsetAsync(acc, 0, (size_t)CH * strip * sizeof(float), stream);
      a_mfma<<<dim3(itiles, CH / 128, ksplit), 256, 0, stream>>>(v, attn, acc, strip, KC);
      add_kernel<<<dim3((CH * rows_this) / 1024), 256, 0, stream>>>(x, acc, out, b, i0s,
                                                                    strip, rows_this);
    }
  }
}

// Round 9
// 577.577 us; speedup vs baseline: 9.1496x; 1.1300x over previous
//
#include <hip/hip_runtime.h>
#include <hip/hip_bf16.h>

typedef __hip_bfloat16 bf16;
typedef __attribute__((ext_vector_type(8))) short short8;   // 8 bf16 MFMA frag
typedef __attribute__((ext_vector_type(4))) float f32x4;    // MFMA acc
typedef __attribute__((ext_vector_type(8))) unsigned short u16x8;
typedef __attribute__((ext_vector_type(4))) unsigned short u16x4;

#define HWSZ 4096
#define CH 512
#define BATCH 4
#define NGROUPS 32
#define CPG 16

// async global->LDS, 16 B per lane; LDS dest is wave-uniform base + lane*16
#define GLL16(gp, lp)                                                         \
  __builtin_amdgcn_global_load_lds(                                           \
      (const __attribute__((address_space(1))) void*)(gp),                    \
      (__attribute__((address_space(3))) void*)(lp), 16, 0, 0)

__device__ __forceinline__ float b2f(bf16 v) { return __bfloat162float(v); }
__device__ __forceinline__ bf16 f2b(float v) { return __float2bfloat16(v); }
__device__ __forceinline__ float u2f(unsigned short u) {
  union { unsigned u; float f; } cv; cv.u = ((unsigned)u) << 16; return cv.f;
}

// ---------------- GN stage 1: partial sums, 8 chunks per (b,g) ----------------
__global__ void gn_part_kernel(const float* __restrict__ x, float2* __restrict__ gpart) {
  int bg = blockIdx.x >> 3, chunk = blockIdx.x & 7;
  size_t base = (size_t)bg * (CPG * HWSZ) + (size_t)chunk * 8192;
  int tid = threadIdx.x;
  float s = 0.f, ss = 0.f;
  const float4* xp = (const float4*)(x + base);
#pragma unroll
  for (int it = 0; it < 8; ++it) {
    float4 v = xp[tid + it * 256];
    s += v.x + v.y + v.z + v.w;
    ss += v.x * v.x + v.y * v.y + v.z * v.z + v.w * v.w;
  }
  __shared__ float rs[256], rss[256];
  rs[tid] = s; rss[tid] = ss;
  __syncthreads();
  for (int off = 128; off > 0; off >>= 1) {
    if (tid < off) { rs[tid] += rs[tid + off]; rss[tid] += rss[tid + off]; }
    __syncthreads();
  }
  if (tid == 0) gpart[blockIdx.x] = make_float2(rs[0], rss[0]);
}

// ---------------- GN stage 2: per-(b,c) scale/shift ----------------
__global__ void gn_final_kernel(const float2* __restrict__ gpart,
                                const float* __restrict__ gw, const float* __restrict__ gb,
                                float* __restrict__ sca, float* __restrict__ shf) {
  int idx = blockIdx.x * 256 + threadIdx.x;
  int b = idx >> 9, c = idx & 511;
  int bg = b * NGROUPS + (c >> 4);
  float s = 0.f, ss = 0.f;
#pragma unroll
  for (int t = 0; t < 8; ++t) {
    float2 p = gpart[bg * 8 + t];
    s += p.x; ss += p.y;
  }
  const float N = (float)(CPG * HWSZ);
  float mu = s / N;
  float var = ss / N - mu * mu;
  float inv = rsqrtf(var + 1e-6f);
  float a = inv * gw[c];
  sca[idx] = a;
  shf[idx] = gb[c] - mu * a;
}

// ---------------- weights f32 -> bf16 (once) ----------------
__global__ void wconv_kernel(const float* __restrict__ qw, const float* __restrict__ kw,
                             const float* __restrict__ vw,
                             bf16* __restrict__ wq, bf16* __restrict__ wk, bf16* __restrict__ wv) {
  int i = blockIdx.x * 256 + threadIdx.x;
  wq[i] = f2b(qw[i]);
  wk[i] = f2b(kw[i]);
  wv[i] = f2b(vw[i]);
}

// ---------------- h_apply: hT[p][c] = bf16(sca[c]*x[b,c,p]+shf[c]) (transpose) -------
__global__ void h_apply_kernel(const float* __restrict__ x, const float* __restrict__ sca,
                               const float* __restrict__ shf, bf16* __restrict__ hT, int b) {
  int p0 = blockIdx.x * 64, c0 = blockIdx.y * 64;
  __shared__ bf16 lt[64][66];
  int t = threadIdx.x;
  int pp = (t & 15) * 4, ccb = t >> 4;
#pragma unroll
  for (int it = 0; it < 4; ++it) {
    int cc = ccb + it * 16;
    int c = c0 + cc;
    float a = sca[b * CH + c], s = shf[b * CH + c];
    const float4 xv = *(const float4*)(x + ((size_t)(b * CH + c)) * HWSZ + p0 + pp);
    lt[cc][pp] = f2b(a * xv.x + s);
    lt[cc][pp + 1] = f2b(a * xv.y + s);
    lt[cc][pp + 2] = f2b(a * xv.z + s);
    lt[cc][pp + 3] = f2b(a * xv.w + s);
  }
  __syncthreads();
  int cc = (t & 15) * 4;
#pragma unroll
  for (int it = 0; it < 4; ++it) {
    int pr = (t >> 4) + it * 16;
    u16x4 o;
#pragma unroll
    for (int j = 0; j < 4; ++j) o[j] = *(const unsigned short*)&lt[cc + j][pr];
    *(u16x4*)(hT + (size_t)(p0 + pr) * CH + c0 + cc) = o;
  }
}

// ---------------- QKV via MFMA (NT), global_load_lds staging ----------------
__global__ __launch_bounds__(256) void qkv_mfma(const bf16* __restrict__ hT,
                                                const bf16* __restrict__ wq,
                                                const bf16* __restrict__ wk,
                                                const bf16* __restrict__ wv,
                                                const float* __restrict__ qb,
                                                const float* __restrict__ kb,
                                                const float* __restrict__ vb,
                                                bf16* __restrict__ qT, bf16* __restrict__ kT,
                                                bf16* __restrict__ v) {
  int p0 = blockIdx.x * 128;
  int o0 = blockIdx.y * 128;
  int z = blockIdx.z;
  const bf16* W = z == 0 ? wq : (z == 1 ? wk : wv);
  const float* bias = z == 0 ? qb : (z == 1 ? kb : vb);
  __shared__ __align__(16) bf16 smem[8960];  // lA[4096] | lB[4096]; v-epilogue reuses 8704
  bf16* lA = smem;
  bf16* lB = smem + 4096;
  int tid = threadIdx.x;
  int l = tid & 63, w = tid >> 6;
  int quad = l >> 4, tm = l & 15;
  int wm = (w & 1) * 64, wn = (w >> 1) * 64;
  int r0 = w * 16 + (l >> 2);   // staging row 0..63
  int ce = (l & 3) * 8;         // staging col (elements)
  bf16* la0 = lA + w * 512;
  bf16* la1 = lA + 2048 + w * 512;
  bf16* lb0 = lB + w * 512;
  bf16* lb1 = lB + 2048 + w * 512;
  const bf16* gA = hT + (size_t)(p0 + r0) * CH + ce;
  const bf16* gA1 = gA + (size_t)64 * CH;
  const bf16* gB = W + (size_t)(o0 + r0) * CH + ce;
  const bf16* gB1 = gB + (size_t)64 * CH;
  f32x4 acc[4][4] = {};
  for (int c0 = 0; c0 < CH; c0 += 32) {
    GLL16(gA + c0, la0);
    GLL16(gA1 + c0, la1);
    GLL16(gB + c0, lb0);
    GLL16(gB1 + c0, lb1);
    __syncthreads();
    short8 aF[4], bF[4];
#pragma unroll
    for (int t = 0; t < 4; ++t) {
      aF[t] = *(const short8*)(lA + (wm + t * 16 + tm) * 32 + quad * 8);
      bF[t] = *(const short8*)(lB + (wn + t * 16 + tm) * 32 + quad * 8);
    }
#pragma unroll
    for (int mt = 0; mt < 4; ++mt)
#pragma unroll
      for (int nt = 0; nt < 4; ++nt)
        acc[mt][nt] = __builtin_amdgcn_mfma_f32_16x16x32_bf16(aF[mt], bF[nt], acc[mt][nt], 0, 0, 0);
    __syncthreads();
  }
  if (z < 2) {
    bf16* outT = z == 0 ? qT : kT;
#pragma unroll
    for (int nt = 0; nt < 4; ++nt) {
      int o = o0 + wn + nt * 16 + tm;
      float bv = bias[o];
#pragma unroll
      for (int mt = 0; mt < 4; ++mt)
#pragma unroll
        for (int r = 0; r < 4; ++r) {
          int p = p0 + wm + mt * 16 + quad * 4 + r;
          outT[(size_t)p * CH + o] = f2b(acc[mt][nt][r] + bv);
        }
    }
  } else {
    // LDS transpose epilogue: v[o][p]
    bf16* lt = smem;  // 64 x 136 = 8704 elems
    for (int chunk = 0; chunk < 2; ++chunk) {
      __syncthreads();
      if (wn == chunk * 64) {
#pragma unroll
        for (int nt = 0; nt < 4; ++nt) {
          int o = o0 + wn + nt * 16 + tm;
          float bv = bias[o];
#pragma unroll
          for (int mt = 0; mt < 4; ++mt)
#pragma unroll
            for (int r = 0; r < 4; ++r)
              lt[(nt * 16 + tm) * 136 + wm + mt * 16 + quad * 4 + r] = f2b(acc[mt][nt][r] + bv);
        }
      }
      __syncthreads();
      int oo = tid >> 2, ppb = (tid & 3) * 32;
      bf16* dst = v + (size_t)(o0 + chunk * 64 + oo) * HWSZ + p0 + ppb;
      const bf16* src = lt + oo * 136 + ppb;
#pragma unroll
      for (int q4 = 0; q4 < 4; ++q4)
        *(u16x8*)(dst + q4 * 8) = *(const u16x8*)(src + q4 * 8);
    }
  }
}

// ---------------- S strip via MFMA (NT), global_load_lds staging ----------------
__global__ __launch_bounds__(256) void s_mfma(const bf16* __restrict__ qT,
                                              const bf16* __restrict__ kT,
                                              bf16* __restrict__ attn, int i0s) {
  int j0 = blockIdx.x * 128;
  int il0 = blockIdx.y * 128;
  int i0 = i0s + il0;
  __shared__ __align__(16) bf16 lA[4096];
  __shared__ __align__(16) bf16 lB[4096];
  int tid = threadIdx.x;
  int l = tid & 63, w = tid >> 6;
  int quad = l >> 4, tm = l & 15;
  int wm = (w & 1) * 64, wn = (w >> 1) * 64;
  int r0 = w * 16 + (l >> 2);
  int ce = (l & 3) * 8;
  bf16* la0 = lA + w * 512;
  bf16* la1 = lA + 2048 + w * 512;
  bf16* lb0 = lB + w * 512;
  bf16* lb1 = lB + 2048 + w * 512;
  const bf16* gA = qT + (size_t)(i0 + r0) * CH + ce;
  const bf16* gA1 = gA + (size_t)64 * CH;
  const bf16* gB = kT + (size_t)(j0 + r0) * CH + ce;
  const bf16* gB1 = gB + (size_t)64 * CH;
  f32x4 acc[4][4] = {};
  for (int c0 = 0; c0 < CH; c0 += 32) {
    GLL16(gA + c0, la0);
    GLL16(gA1 + c0, la1);
    GLL16(gB + c0, lb0);
    GLL16(gB1 + c0, lb1);
    __syncthreads();
    short8 aF[4], bF[4];
#pragma unroll
    for (int t = 0; t < 4; ++t) {
      aF[t] = *(const short8*)(lA + (wm + t * 16 + tm) * 32 + quad * 8);
      bF[t] = *(const short8*)(lB + (wn + t * 16 + tm) * 32 + quad * 8);
    }
#pragma unroll
    for (int mt = 0; mt < 4; ++mt)
#pragma unroll
      for (int nt = 0; nt < 4; ++nt)
        acc[mt][nt] = __builtin_amdgcn_mfma_f32_16x16x32_bf16(aF[mt], bF[nt], acc[mt][nt], 0, 0, 0);
    __syncthreads();
  }
  const float scale = 0.044194173824159216f;  // 512^-0.5
#pragma unroll
  for (int mt = 0; mt < 4; ++mt)
#pragma unroll
    for (int nt = 0; nt < 4; ++nt)
#pragma unroll
      for (int r = 0; r < 4; ++r) {
        int il = il0 + wm + mt * 16 + quad * 4 + r;
        int j = j0 + wn + nt * 16 + tm;
        attn[(size_t)il * HWSZ + j] = f2b(acc[mt][nt][r] * scale);
      }
}

// ---------------- row softmax, vectorized u16x8 ----------------
__global__ void softmax_kernel(bf16* __restrict__ attn) {
  int i = blockIdx.x;
  int tid = threadIdx.x;
  __shared__ float row[HWSZ];
  __shared__ float red[256];
  u16x8* r = (u16x8*)(attn + (size_t)i * HWSZ);
  float m = -1e30f;
#pragma unroll
  for (int it = 0; it < 2; ++it) {
    int j8 = tid + it * 256;
    u16x8 rv = r[j8];
#pragma unroll
    for (int t = 0; t < 8; ++t) {
      float v = u2f(rv[t]);
      row[j8 * 8 + t] = v;
      m = fmaxf(m, v);
    }
  }
  red[tid] = m;
  __syncthreads();
  for (int off = 128; off > 0; off >>= 1) {
    if (tid < off) red[tid] = fmaxf(red[tid], red[tid + off]);
    __syncthreads();
  }
  m = red[0];
  __syncthreads();
  float s = 0.f;
  for (int j = tid; j < HWSZ; j += 256) {
    float e = __expf(row[j] - m);
    row[j] = e;
    s += e;
  }
  red[tid] = s;
  __syncthreads();
  for (int off = 128; off > 0; off >>= 1) {
    if (tid < off) red[tid] += red[tid + off];
    __syncthreads();
  }
  float inv = 1.0f / red[0];
  __syncthreads();
#pragma unroll
  for (int it = 0; it < 2; ++it) {
    int j8 = tid + it * 256;
    u16x8 o;
#pragma unroll
    for (int t = 0; t < 8; ++t) {
      bf16 bv = f2b(row[j8 * 8 + t] * inv);
      o[t] = *(unsigned short*)&bv;
    }
    r[j8] = o;
  }
}

// ---------------- A strip via MFMA + split-K atomics, global_load_lds staging ----------
__global__ __launch_bounds__(256) void a_mfma(const bf16* __restrict__ v,
                                              const bf16* __restrict__ attn,
                                              float* __restrict__ acc_out, int strip, int KC) {
  int il0 = blockIdx.x * 128;
  int c00 = blockIdx.y * 128;
  int kbase = blockIdx.z * KC;
  __shared__ __align__(16) bf16 lA[4096];
  __shared__ __align__(16) bf16 lB[4096];
  int tid = threadIdx.x;
  int l = tid & 63, w = tid >> 6;
  int quad = l >> 4, tm = l & 15;
  int wm = (w & 1) * 64, wn = (w >> 1) * 64;
  int r0 = w * 16 + (l >> 2);
  int ce = (l & 3) * 8;
  bf16* la0 = lA + w * 512;
  bf16* la1 = lA + 2048 + w * 512;
  bf16* lb0 = lB + w * 512;
  bf16* lb1 = lB + 2048 + w * 512;
  const bf16* gA = v + (size_t)(c00 + r0) * HWSZ + kbase + ce;
  const bf16* gA1 = gA + (size_t)64 * HWSZ;
  const bf16* gB = attn + (size_t)(il0 + r0) * HWSZ + kbase + ce;
  const bf16* gB1 = gB + (size_t)64 * HWSZ;
  f32x4 acc[4][4] = {};
  for (int k0 = 0; k0 < KC; k0 += 32) {
    GLL16(gA + k0, la0);
    GLL16(gA1 + k0, la1);
    GLL16(gB + k0, lb0);
    GLL16(gB1 + k0, lb1);
    __syncthreads();
    short8 aF[4], bF[4];
#pragma unroll
    for (int t = 0; t < 4; ++t) {
      aF[t] = *(const short8*)(lA + (wm + t * 16 + tm) * 32 + quad * 8);
      bF[t] = *(const short8*)(lB + (wn + t * 16 + tm) * 32 + quad * 8);
    }
#pragma unroll
    for (int mt = 0; mt < 4; ++mt)
#pragma unroll
      for (int nt = 0; nt < 4; ++nt)
        acc[mt][nt] = __builtin_amdgcn_mfma_f32_16x16x32_bf16(aF[mt], bF[nt], acc[mt][nt], 0, 0, 0);
    __syncthreads();
  }
#pragma unroll
  for (int mt = 0; mt < 4; ++mt)
#pragma unroll
    for (int nt = 0; nt < 4; ++nt)
#pragma unroll
      for (int r = 0; r < 4; ++r) {
        int c = c00 + wm + mt * 16 + quad * 4 + r;
        int il = il0 + wn + nt * 16 + tm;
        atomicAdd(&acc_out[(size_t)c * strip + il], acc[mt][nt][r]);
      }
}

// ---------------- out[b,c,i0s+il] = x + acc ----------------
__global__ void add_kernel(const float* __restrict__ x, const float* __restrict__ acc,
                           float* __restrict__ out, int b, int i0s, int strip, int rows) {
  int idx = blockIdx.x * 256 + threadIdx.x;
  int per_row = rows >> 2;
  int c = idx / per_row;
  int r4 = (idx - c * per_row) * 4;
  size_t g = ((size_t)(b * CH + c)) * HWSZ + i0s + r4;
  const float4 xv = *(const float4*)(x + g);
  const float4 av = *(const float4*)(acc + (size_t)c * strip + r4);
  float4 o;
  o.x = xv.x + av.x; o.y = xv.y + av.y; o.z = xv.z + av.z; o.w = xv.w + av.w;
  *(float4*)(out + g) = o;
}

extern "C" void kernel_launch(void* const* d_in, const int* in_sizes, int n_in,
                              void* d_out, int out_size, void* d_ws, size_t ws_size,
                              hipStream_t stream) {
  const float* x   = (const float*)d_in[0];
  const float* gnw = (const float*)d_in[1];
  const float* gnb = (const float*)d_in[2];
  const float* qw  = (const float*)d_in[3];
  const float* qb  = (const float*)d_in[4];
  const float* kw  = (const float*)d_in[5];
  const float* kb  = (const float*)d_in[6];
  const float* vw  = (const float*)d_in[7];
  const float* vb  = (const float*)d_in[8];
  float* out = (float*)d_out;

  char* ws = (char*)d_ws;
  float* sca = (float*)ws;
  float* shf = sca + BATCH * CH;
  float2* gpart = (float2*)(ws + 16384);
  const size_t wsz = (size_t)CH * CH;
  const size_t per = (size_t)CH * HWSZ;
  bf16* wqb = (bf16*)(ws + 32768);
  bf16* wkb = wqb + wsz;
  bf16* wvb = wkb + wsz;
  bf16* hT = wvb + wsz;
  bf16* qT = hT + per;
  bf16* kT = qT + per;
  bf16* v  = kT + per;
  size_t used0 = 32768 + 3 * wsz * sizeof(bf16) + 4 * per * sizeof(bf16);  // ~17.5 MB
  long rows = ((long)ws_size - (long)used0) / 10240;  // attn 8KB + acc 2KB per row
  rows = (rows / 128) * 128;
  if (rows < 128) rows = 128;
  if (rows > 4096) rows = 4096;
  int strip = (int)rows;
  bf16* attn = v + per;
  float* acc = (float*)((char*)attn + (size_t)strip * HWSZ * sizeof(bf16));

  gn_part_kernel<<<dim3(BATCH * NGROUPS * 8), 256, 0, stream>>>(x, gpart);
  gn_final_kernel<<<dim3(8), 256, 0, stream>>>(gpart, gnw, gnb, sca, shf);
  wconv_kernel<<<dim3(wsz / 256), 256, 0, stream>>>(qw, kw, vw, wqb, wkb, wvb);
  for (int b = 0; b < BATCH; ++b) {
    h_apply_kernel<<<dim3(HWSZ / 64, CH / 64), 256, 0, stream>>>(x, sca, shf, hT, b);
    qkv_mfma<<<dim3(HWSZ / 128, CH / 128, 3), 256, 0, stream>>>(hT, wqb, wkb, wvb, qb, kb, vb,
                                                                qT, kT, v);
    for (int i0s = 0; i0s < HWSZ; i0s += strip) {
      int rows_this = HWSZ - i0s < strip ? HWSZ - i0s : strip;
      int itiles = rows_this / 128;
      // target >= 512 blocks (2 per CU) for a_mfma
      int ksplit = 512 / (itiles * (CH / 128));
      if (ksplit < 1) ksplit = 1;
      if (ksplit > 8) ksplit = 8;
      while (ksplit & (ksplit - 1)) --ksplit;
      int KC = HWSZ / ksplit;
      s_mfma<<<dim3(HWSZ / 128, itiles), 256, 0, stream>>>(qT, kT, attn, i0s);
      softmax_kernel<<<dim3(rows_this), 256, 0, stream>>>(attn);
      hipMemsetAsync(acc, 0, (size_t)CH * strip * sizeof(float), stream);
      a_mfma<<<dim3(itiles, CH / 128, ksplit), 256, 0, stream>>>(v, attn, acc, strip, KC);
      add_kernel<<<dim3((CH * rows_this) / 1024), 256, 0, stream>>>(x, acc, out, b, i0s,
                                                                    strip, rows_this);
    }
  }
}